// Round 1
// baseline (360.047 us; speedup 1.0000x reference)
//
#include <hip/hip_runtime.h>
#include <hip/hip_bf16.h>
#include <math.h>

#define B_   64
#define C_   768
#define C2_  1536
#define R_   96
#define E_   16
#define HW_  1024

__device__ __forceinline__ float gelu_exact(float x) {
    return 0.5f * x * (1.0f + erff(x * 0.70710678118654752440f));
}

// ---------------- Kernel 1: global average pool [B,C,H,W] -> g[B,C] ----------
// one wave (64 lanes) per (b,c) row of 1024 contiguous floats
__global__ __launch_bounds__(256) void pool_kernel(const float* __restrict__ x,
                                                   float* __restrict__ g) {
    const int wave = threadIdx.x >> 6;
    const int lane = threadIdx.x & 63;
    const int row  = blockIdx.x * 4 + wave;   // row < B_*C_ guaranteed by grid
    const float4* p = reinterpret_cast<const float4*>(x + (size_t)row * HW_);
    float4 a0 = p[lane +   0];
    float4 a1 = p[lane +  64];
    float4 a2 = p[lane + 128];
    float4 a3 = p[lane + 192];
    float s = (a0.x + a0.y + a0.z + a0.w) + (a1.x + a1.y + a1.z + a1.w)
            + (a2.x + a2.y + a2.z + a2.w) + (a3.x + a3.y + a3.z + a3.w);
    #pragma unroll
    for (int off = 32; off >= 1; off >>= 1) s += __shfl_xor(s, off);
    if (lane == 0) g[row] = s * (1.0f / (float)HW_);
}

// ---------------- Kernel 2: per-row gating chain ----------------------------
// one block of 256 threads per batch row
__global__ __launch_bounds__(256) void gating_kernel(
    const float* __restrict__ g,
    const float* __restrict__ w1,  const float* __restrict__ b1,
    const float* __restrict__ bn1_g, const float* __restrict__ bn1_b,
    const float* __restrict__ bn1_m, const float* __restrict__ bn1_v,
    const float* __restrict__ caw1, const float* __restrict__ cab1,
    const float* __restrict__ caw2, const float* __restrict__ cab2,
    const float* __restrict__ w2,  const float* __restrict__ b2,
    const float* __restrict__ bn2_g, const float* __restrict__ bn2_b,
    const float* __restrict__ bn2_m, const float* __restrict__ bn2_v,
    const float* __restrict__ w3,  const float* __restrict__ b3,
    float* __restrict__ out)
{
    __shared__ __align__(16) float sg[C_];    // pooled input row
    __shared__ __align__(16) float h[C2_];    // h1 then h (post-CA)
    __shared__ __align__(16) float r[R_];     // CA bottleneck
    __shared__ __align__(16) float h2[C_];    // second hidden
    __shared__ float sc[E_];                  // expert scores

    const int b = blockIdx.x;
    const int t = threadIdx.x;

    for (int i = t; i < C_; i += 256) sg[i] = g[b * C_ + i];
    __syncthreads();

    // h1 = gelu(bn1(g @ w1.T + b1)) : 1536 outputs, dot over 768
    for (int c = t; c < C2_; c += 256) {
        const float4* wr = reinterpret_cast<const float4*>(w1 + (size_t)c * C_);
        const float4* gv = reinterpret_cast<const float4*>(sg);
        float ax = 0.f, ay = 0.f, az = 0.f, aw = 0.f;
        #pragma unroll 4
        for (int k = 0; k < C_ / 4; ++k) {
            float4 wv = wr[k]; float4 gg = gv[k];
            ax = fmaf(wv.x, gg.x, ax);
            ay = fmaf(wv.y, gg.y, ay);
            az = fmaf(wv.z, gg.z, az);
            aw = fmaf(wv.w, gg.w, aw);
        }
        float acc = (ax + ay) + (az + aw) + b1[c];
        acc = (acc - bn1_m[c]) * rsqrtf(bn1_v[c] + 1e-5f) * bn1_g[c] + bn1_b[c];
        h[c] = gelu_exact(acc);
    }
    __syncthreads();

    // r = gelu(h @ caw1.T + cab1) : 96 outputs, dot over 1536
    if (t < R_) {
        const float4* wr = reinterpret_cast<const float4*>(caw1 + (size_t)t * C2_);
        const float4* hv = reinterpret_cast<const float4*>(h);
        float ax = 0.f, ay = 0.f, az = 0.f, aw = 0.f;
        #pragma unroll 4
        for (int k = 0; k < C2_ / 4; ++k) {
            float4 wv = wr[k]; float4 hh = hv[k];
            ax = fmaf(wv.x, hh.x, ax);
            ay = fmaf(wv.y, hh.y, ay);
            az = fmaf(wv.z, hh.z, az);
            aw = fmaf(wv.w, hh.w, aw);
        }
        r[t] = gelu_exact((ax + ay) + (az + aw) + cab1[t]);
    }
    __syncthreads();

    // a = r @ caw2.T + cab2 ; h *= sigmoid(2a)
    for (int c = t; c < C2_; c += 256) {
        const float* wr = caw2 + (size_t)c * R_;
        float acc = 0.f;
        #pragma unroll 8
        for (int k = 0; k < R_; ++k) acc = fmaf(r[k], wr[k], acc);
        acc += cab2[c];
        float sig = 1.0f / (1.0f + expf(-2.0f * acc));
        h[c] = h[c] * sig;
    }
    __syncthreads();

    // h2 = gelu(bn2(h @ w2.T + b2)) : 768 outputs, dot over 1536
    for (int c = t; c < C_; c += 256) {
        const float4* wr = reinterpret_cast<const float4*>(w2 + (size_t)c * C2_);
        const float4* hv = reinterpret_cast<const float4*>(h);
        float ax = 0.f, ay = 0.f, az = 0.f, aw = 0.f;
        #pragma unroll 4
        for (int k = 0; k < C2_ / 4; ++k) {
            float4 wv = wr[k]; float4 hh = hv[k];
            ax = fmaf(wv.x, hh.x, ax);
            ay = fmaf(wv.y, hh.y, ay);
            az = fmaf(wv.z, hh.z, az);
            aw = fmaf(wv.w, hh.w, aw);
        }
        float acc = (ax + ay) + (az + aw) + b2[c];
        acc = (acc - bn2_m[c]) * rsqrtf(bn2_v[c] + 1e-5f) * bn2_g[c] + bn2_b[c];
        h2[c] = gelu_exact(acc);
    }
    __syncthreads();

    // scores = h2 @ w3.T + b3 : 16 outputs, dot over 768
    if (t < E_) {
        const float4* wr = reinterpret_cast<const float4*>(w3 + (size_t)t * C_);
        const float4* hv = reinterpret_cast<const float4*>(h2);
        float ax = 0.f, ay = 0.f, az = 0.f, aw = 0.f;
        #pragma unroll 4
        for (int k = 0; k < C_ / 4; ++k) {
            float4 wv = wr[k]; float4 hh = hv[k];
            ax = fmaf(wv.x, hh.x, ax);
            ay = fmaf(wv.y, hh.y, ay);
            az = fmaf(wv.z, hh.z, az);
            aw = fmaf(wv.w, hh.w, aw);
        }
        sc[t] = (ax + ay) + (az + aw) + b3[t];
    }
    __syncthreads();

    // top-2 (first-occurrence ties, like jax.lax.top_k) + softmax(vals/2)
    if (t == 0) {
        int i0 = 0; float v0 = sc[0];
        #pragma unroll
        for (int i = 1; i < E_; ++i) { if (sc[i] > v0) { v0 = sc[i]; i0 = i; } }
        int i1 = -1; float v1 = -INFINITY;
        #pragma unroll
        for (int i = 0; i < E_; ++i) {
            if (i == i0) continue;
            if (sc[i] > v1) { v1 = sc[i]; i1 = i; }
        }
        // softmax([v0, v1] / 2), v0 >= v1
        float e1 = expf((v1 - v0) * 0.5f);
        float inv = 1.0f / (1.0f + e1);
        // output layout: idx[64,2] as float, then probs[64,2]
        out[b * 2 + 0] = (float)i0;
        out[b * 2 + 1] = (float)i1;
        out[2 * B_ + b * 2 + 0] = inv;
        out[2 * B_ + b * 2 + 1] = e1 * inv;
    }
}

extern "C" void kernel_launch(void* const* d_in, const int* in_sizes, int n_in,
                              void* d_out, int out_size, void* d_ws, size_t ws_size,
                              hipStream_t stream) {
    const float* x     = (const float*)d_in[0];
    const float* w1    = (const float*)d_in[1];
    const float* b1    = (const float*)d_in[2];
    const float* bn1_g = (const float*)d_in[3];
    const float* bn1_b = (const float*)d_in[4];
    const float* bn1_m = (const float*)d_in[5];
    const float* bn1_v = (const float*)d_in[6];
    const float* caw1  = (const float*)d_in[7];
    const float* cab1  = (const float*)d_in[8];
    const float* caw2  = (const float*)d_in[9];
    const float* cab2  = (const float*)d_in[10];
    const float* w2    = (const float*)d_in[11];
    const float* b2    = (const float*)d_in[12];
    const float* bn2_g = (const float*)d_in[13];
    const float* bn2_b = (const float*)d_in[14];
    const float* bn2_m = (const float*)d_in[15];
    const float* bn2_v = (const float*)d_in[16];
    const float* w3    = (const float*)d_in[17];
    const float* b3    = (const float*)d_in[18];

    float* g = (float*)d_ws;                 // [64,768] pooled
    float* out = (float*)d_out;

    pool_kernel<<<(B_ * C_) / 4, 256, 0, stream>>>(x, g);
    gating_kernel<<<B_, 256, 0, stream>>>(g, w1, b1, bn1_g, bn1_b, bn1_m, bn1_v,
                                          caw1, cab1, caw2, cab2,
                                          w2, b2, bn2_g, bn2_b, bn2_m, bn2_v,
                                          w3, b3, out);
}

// Round 2
// 179.245 us; speedup vs baseline: 2.0087x; 2.0087x over previous
//
#include <hip/hip_runtime.h>
#include <hip/hip_bf16.h>
#include <math.h>

#define B_   64
#define C_   768
#define C2_  1536
#define R_   96
#define E_   16
#define HW_  1024

__device__ __forceinline__ float gelu_exact(float x) {
    return 0.5f * x * (1.0f + erff(x * 0.70710678118654752440f));
}

// -------- Kernel 1: global average pool [B,C,H,W] -> gT[C][B] (transposed) --
// one wave (64 lanes) per (b,c) row of 1024 contiguous floats
__global__ __launch_bounds__(256) void pool_kernel(const float* __restrict__ x,
                                                   float* __restrict__ gT) {
    const int wave = threadIdx.x >> 6;
    const int lane = threadIdx.x & 63;
    const int row  = blockIdx.x * 4 + wave;   // row in [0, B_*C_)
    const int b = row / C_;
    const int c = row % C_;
    const float4* p = reinterpret_cast<const float4*>(x + (size_t)row * HW_);
    float4 a0 = p[lane +   0];
    float4 a1 = p[lane +  64];
    float4 a2 = p[lane + 128];
    float4 a3 = p[lane + 192];
    float s = (a0.x + a0.y + a0.z + a0.w) + (a1.x + a1.y + a1.z + a1.w)
            + (a2.x + a2.y + a2.z + a2.w) + (a3.x + a3.y + a3.z + a3.w);
    #pragma unroll
    for (int off = 32; off >= 1; off >>= 1) s += __shfl_xor(s, off);
    if (lane == 0) gT[c * B_ + b] = s * (1.0f / (float)HW_);
}

// -------- L1: h1T = gelu(bn1(gT^T @ w1.T)) — 4 out-channels per block -------
// thread (ci,b): dot over K=768. gT reads coalesced (64 consecutive b),
// w1 row staged in LDS, broadcast across lanes.
__global__ __launch_bounds__(256) void l1_kernel(
    const float* __restrict__ gT, const float* __restrict__ w1,
    const float* __restrict__ b1,
    const float* __restrict__ bn_g, const float* __restrict__ bn_b,
    const float* __restrict__ bn_m, const float* __restrict__ bn_v,
    float* __restrict__ h1T)
{
    __shared__ __align__(16) float wl[4 * C_];
    const int t  = threadIdx.x;
    const int c0 = blockIdx.x * 4;
    {
        const float4* src = reinterpret_cast<const float4*>(w1 + (size_t)c0 * C_);
        float4* dst = reinterpret_cast<float4*>(wl);
        #pragma unroll
        for (int i = 0; i < 3; ++i) dst[t + 256 * i] = src[t + 256 * i];
    }
    __syncthreads();
    const int ci = t >> 6, b = t & 63, c = c0 + ci;
    const float* wr = wl + ci * C_;
    float acc = 0.f;
    #pragma unroll 8
    for (int k = 0; k < C_; ++k) acc = fmaf(gT[k * B_ + b], wr[k], acc);
    acc += b1[c];
    acc = (acc - bn_m[c]) * rsqrtf(bn_v[c] + 1e-5f) * bn_g[c] + bn_b[c];
    h1T[c * B_ + b] = gelu_exact(acc);
}

// -------- L2: rT = gelu(h1 @ caw1.T) — K=1536, 96 outputs ------------------
__global__ __launch_bounds__(256) void l2_kernel(
    const float* __restrict__ h1T, const float* __restrict__ caw1,
    const float* __restrict__ cab1, float* __restrict__ rT)
{
    __shared__ __align__(16) float wl[4 * C2_];
    const int t  = threadIdx.x;
    const int c0 = blockIdx.x * 4;
    {
        const float4* src = reinterpret_cast<const float4*>(caw1 + (size_t)c0 * C2_);
        float4* dst = reinterpret_cast<float4*>(wl);
        #pragma unroll
        for (int i = 0; i < 6; ++i) dst[t + 256 * i] = src[t + 256 * i];
    }
    __syncthreads();
    const int ci = t >> 6, b = t & 63, c = c0 + ci;
    const float* wr = wl + ci * C2_;
    float acc = 0.f;
    #pragma unroll 8
    for (int k = 0; k < C2_; ++k) acc = fmaf(h1T[k * B_ + b], wr[k], acc);
    rT[c * B_ + b] = gelu_exact(acc + cab1[c]);
}

// -------- L3: a = r @ caw2.T ; h1T *= sigmoid(2a)  (in-place gate) ---------
__global__ __launch_bounds__(256) void l3_kernel(
    const float* __restrict__ rT, const float* __restrict__ caw2,
    const float* __restrict__ cab2, float* __restrict__ h1T)
{
    __shared__ float wl[4 * R_];
    const int t  = threadIdx.x;
    const int c0 = blockIdx.x * 4;
    if (t < 4 * R_) wl[t] = caw2[(size_t)c0 * R_ + t];
    __syncthreads();
    const int ci = t >> 6, b = t & 63, c = c0 + ci;
    const float* wr = wl + ci * R_;
    float acc = 0.f;
    #pragma unroll 8
    for (int k = 0; k < R_; ++k) acc = fmaf(rT[k * B_ + b], wr[k], acc);
    acc += cab2[c];
    float sig = 1.0f / (1.0f + expf(-2.0f * acc));
    h1T[c * B_ + b] *= sig;
}

// -------- L4: h2T = gelu(bn2(h @ w2.T)) — K=1536, 768 outputs --------------
__global__ __launch_bounds__(256) void l4_kernel(
    const float* __restrict__ h1T, const float* __restrict__ w2,
    const float* __restrict__ b2,
    const float* __restrict__ bn_g, const float* __restrict__ bn_b,
    const float* __restrict__ bn_m, const float* __restrict__ bn_v,
    float* __restrict__ h2T)
{
    __shared__ __align__(16) float wl[4 * C2_];
    const int t  = threadIdx.x;
    const int c0 = blockIdx.x * 4;
    {
        const float4* src = reinterpret_cast<const float4*>(w2 + (size_t)c0 * C2_);
        float4* dst = reinterpret_cast<float4*>(wl);
        #pragma unroll
        for (int i = 0; i < 6; ++i) dst[t + 256 * i] = src[t + 256 * i];
    }
    __syncthreads();
    const int ci = t >> 6, b = t & 63, c = c0 + ci;
    const float* wr = wl + ci * C2_;
    float acc = 0.f;
    #pragma unroll 8
    for (int k = 0; k < C2_; ++k) acc = fmaf(h1T[k * B_ + b], wr[k], acc);
    acc += b2[c];
    acc = (acc - bn_m[c]) * rsqrtf(bn_v[c] + 1e-5f) * bn_g[c] + bn_b[c];
    h2T[c * B_ + b] = gelu_exact(acc);
}

// -------- L5: scores + top-2 + softmax, one block per batch row ------------
// 256 threads: e = t&15 (expert), kg = t>>4 (k-group of 48)
__global__ __launch_bounds__(256) void l5_kernel(
    const float* __restrict__ h2T, const float* __restrict__ w3,
    const float* __restrict__ b3, float* __restrict__ out)
{
    __shared__ __align__(16) float wl[E_ * C_];   // 48 KB
    __shared__ float part[256];
    __shared__ float sc[E_];
    const int t = threadIdx.x;
    const int b = blockIdx.x;
    {
        const float4* src = reinterpret_cast<const float4*>(w3);
        float4* dst = reinterpret_cast<float4*>(wl);
        #pragma unroll
        for (int i = 0; i < 12; ++i) dst[t + 256 * i] = src[t + 256 * i];
    }
    __syncthreads();
    const int e = t & 15, kg = t >> 4;            // kg in [0,16)
    const float* wr = wl + e * C_ + kg * 48;
    const float* hv = h2T + (size_t)kg * 48 * B_ + b;
    float acc = 0.f;
    #pragma unroll 8
    for (int j = 0; j < 48; ++j) acc = fmaf(hv[j * B_], wr[j], acc);
    part[t] = acc;
    __syncthreads();
    if (t < E_) {
        float s = b3[t];
        #pragma unroll
        for (int kgi = 0; kgi < 16; ++kgi) s += part[kgi * 16 + t];
        sc[t] = s;
    }
    __syncthreads();
    if (t == 0) {
        int i0 = 0; float v0 = sc[0];
        #pragma unroll
        for (int i = 1; i < E_; ++i) { if (sc[i] > v0) { v0 = sc[i]; i0 = i; } }
        int i1 = -1; float v1 = -INFINITY;
        #pragma unroll
        for (int i = 0; i < E_; ++i) {
            if (i == i0) continue;
            if (sc[i] > v1) { v1 = sc[i]; i1 = i; }
        }
        float e1 = expf((v1 - v0) * 0.5f);
        float inv = 1.0f / (1.0f + e1);
        out[b * 2 + 0] = (float)i0;
        out[b * 2 + 1] = (float)i1;
        out[2 * B_ + b * 2 + 0] = inv;
        out[2 * B_ + b * 2 + 1] = e1 * inv;
    }
}

extern "C" void kernel_launch(void* const* d_in, const int* in_sizes, int n_in,
                              void* d_out, int out_size, void* d_ws, size_t ws_size,
                              hipStream_t stream) {
    const float* x     = (const float*)d_in[0];
    const float* w1    = (const float*)d_in[1];
    const float* b1    = (const float*)d_in[2];
    const float* bn1_g = (const float*)d_in[3];
    const float* bn1_b = (const float*)d_in[4];
    const float* bn1_m = (const float*)d_in[5];
    const float* bn1_v = (const float*)d_in[6];
    const float* caw1  = (const float*)d_in[7];
    const float* cab1  = (const float*)d_in[8];
    const float* caw2  = (const float*)d_in[9];
    const float* cab2  = (const float*)d_in[10];
    const float* w2    = (const float*)d_in[11];
    const float* b2    = (const float*)d_in[12];
    const float* bn2_g = (const float*)d_in[13];
    const float* bn2_b = (const float*)d_in[14];
    const float* bn2_m = (const float*)d_in[15];
    const float* bn2_v = (const float*)d_in[16];
    const float* w3    = (const float*)d_in[17];
    const float* b3    = (const float*)d_in[18];

    float* ws  = (float*)d_ws;
    float* gT  = ws;                    // [768][64]
    float* h1T = ws + 49152;            // [1536][64]
    float* rT  = ws + 49152 + 98304;    // [96][64]
    float* h2T = ws + 49152 + 98304 + 6144;  // [768][64]
    float* out = (float*)d_out;

    pool_kernel<<<(B_ * C_) / 4, 256, 0, stream>>>(x, gT);
    l1_kernel<<<C2_ / 4, 256, 0, stream>>>(gT, w1, b1, bn1_g, bn1_b, bn1_m, bn1_v, h1T);
    l2_kernel<<<R_ / 4, 256, 0, stream>>>(h1T, caw1, cab1, rT);
    l3_kernel<<<C2_ / 4, 256, 0, stream>>>(rT, caw2, cab2, h1T);
    l4_kernel<<<C_ / 4, 256, 0, stream>>>(h1T, w2, b2, bn2_g, bn2_b, bn2_m, bn2_v, h2T);
    l5_kernel<<<B_, 256, 0, stream>>>(h2T, w3, b3, out);
}

// Round 3
// 72.218 us; speedup vs baseline: 4.9856x; 2.4820x over previous
//
#include <hip/hip_runtime.h>
#include <hip/hip_bf16.h>
#include <math.h>

#define B_   64
#define C_   768
#define C2_  1536
#define R_   96
#define E_   16
#define HW_  1024

__device__ __forceinline__ float gelu_exact(float x) {
    return 0.5f * x * (1.0f + erff(x * 0.70710678118654752440f));
}

// -------- Kernel 1: global average pool [B,C,H,W] -> gT[C][B] (transposed) --
// one wave (64 lanes) per (b,c) row of 1024 contiguous floats. HBM-bound.
__global__ __launch_bounds__(256) void pool_kernel(const float* __restrict__ x,
                                                   float* __restrict__ gT) {
    const int wave = threadIdx.x >> 6;
    const int lane = threadIdx.x & 63;
    const int row  = blockIdx.x * 4 + wave;   // row in [0, B_*C_)
    const int b = row / C_;
    const int c = row % C_;
    const float4* p = reinterpret_cast<const float4*>(x + (size_t)row * HW_);
    float4 a0 = p[lane +   0];
    float4 a1 = p[lane +  64];
    float4 a2 = p[lane + 128];
    float4 a3 = p[lane + 192];
    float s = (a0.x + a0.y + a0.z + a0.w) + (a1.x + a1.y + a1.z + a1.w)
            + (a2.x + a2.y + a2.z + a2.w) + (a3.x + a3.y + a3.z + a3.w);
    #pragma unroll
    for (int off = 32; off >= 1; off >>= 1) s += __shfl_xor(s, off);
    if (lane == 0) gT[c * B_ + b] = s * (1.0f / (float)HW_);
}

// -------- Generic fused GEMV layer: outT = gelu([BN](inT^T @ W.T + bias)) ---
// 512 threads = 8 waves. Block computes a c-tile of 2 outputs x all 64 b.
// Wave w owns K-chunk w (K/8 long) and accumulates BOTH c's (input loaded
// once, 2 fmaf per element -> ILP 2, chain K/8). LDS tree-reduce at the end.
template<int K, bool BN>
__global__ __launch_bounds__(512) void gemv2_kernel(
    const float* __restrict__ inT,   // [K][64]
    const float* __restrict__ W,     // [Cout][K]
    const float* __restrict__ bias,
    const float* __restrict__ bn_g, const float* __restrict__ bn_b,
    const float* __restrict__ bn_m, const float* __restrict__ bn_v,
    float* __restrict__ outT)        // [Cout][64]
{
    __shared__ __align__(16) float wl[2 * K];
    __shared__ float part[2][8][64];
    const int t  = threadIdx.x;
    const int c0 = blockIdx.x * 2;
    {   // stage 2 weight rows (2K floats = K/2 float4)
        const float4* src = reinterpret_cast<const float4*>(W + (size_t)c0 * K);
        float4* dst = reinterpret_cast<float4*>(wl);
        #pragma unroll
        for (int i = t; i < K / 2; i += 512) dst[i] = src[i];
    }
    __syncthreads();
    const int b = t & 63, w = t >> 6;          // wave id = K-chunk
    const int kc = w * (K / 8);
    const float* w0 = wl + kc;
    const float* w1 = wl + K + kc;
    const float* g  = inT + (size_t)kc * B_ + b;
    float a0 = 0.f, a1 = 0.f;
    #pragma unroll 16
    for (int k = 0; k < K / 8; ++k) {
        float gv = g[k * B_];                  // coalesced across lanes
        a0 = fmaf(gv, w0[k], a0);              // LDS broadcast reads
        a1 = fmaf(gv, w1[k], a1);
    }
    part[0][w][b] = a0;
    part[1][w][b] = a1;
    __syncthreads();
    if (t < 128) {
        const int ci = t >> 6, bb = t & 63, c = c0 + ci;
        float s = (part[ci][0][bb] + part[ci][1][bb])
                + (part[ci][2][bb] + part[ci][3][bb])
                + (part[ci][4][bb] + part[ci][5][bb])
                + (part[ci][6][bb] + part[ci][7][bb]);
        s += bias[c];
        if (BN) s = (s - bn_m[c]) * rsqrtf(bn_v[c] + 1e-5f) * bn_g[c] + bn_b[c];
        outT[(size_t)c * B_ + bb] = gelu_exact(s);
    }
}

// -------- L3: a = r @ caw2.T + cab2 ; h1T *= sigmoid(2a) (in-place) --------
// 512 threads = 8 waves, one c per wave, lane = b, chain K=96.
__global__ __launch_bounds__(512) void gate_kernel(
    const float* __restrict__ rT,    // [96][64]
    const float* __restrict__ caw2,  // [1536][96]
    const float* __restrict__ cab2,
    float* __restrict__ h1T)         // [1536][64] in-place
{
    const int t = threadIdx.x;
    const int b = t & 63, w = t >> 6;
    const int c = blockIdx.x * 8 + w;
    const float* wr = caw2 + (size_t)c * R_;   // wave-uniform (broadcast)
    float acc = 0.f;
    #pragma unroll 12
    for (int k = 0; k < R_; ++k) acc = fmaf(rT[k * B_ + b], wr[k], acc);
    acc += cab2[c];
    float sig = 1.0f / (1.0f + expf(-2.0f * acc));
    h1T[(size_t)c * B_ + b] *= sig;
}

// -------- L5: scores + top-2 + softmax, one block per batch row ------------
__global__ __launch_bounds__(256) void l5_kernel(
    const float* __restrict__ h2T, const float* __restrict__ w3,
    const float* __restrict__ b3, float* __restrict__ out)
{
    __shared__ __align__(16) float wl[E_ * C_];   // 48 KB
    __shared__ float part[256];
    __shared__ float sc[E_];
    const int t = threadIdx.x;
    const int b = blockIdx.x;
    {
        const float4* src = reinterpret_cast<const float4*>(w3);
        float4* dst = reinterpret_cast<float4*>(wl);
        #pragma unroll
        for (int i = 0; i < 12; ++i) dst[t + 256 * i] = src[t + 256 * i];
    }
    __syncthreads();
    const int e = t & 15, kg = t >> 4;            // kg in [0,16)
    const float* wr = wl + e * C_ + kg * 48;
    const float* hv = h2T + (size_t)kg * 48 * B_ + b;
    float acc = 0.f;
    #pragma unroll 8
    for (int j = 0; j < 48; ++j) acc = fmaf(hv[j * B_], wr[j], acc);
    part[t] = acc;
    __syncthreads();
    if (t < E_) {
        float s = b3[t];
        #pragma unroll
        for (int kgi = 0; kgi < 16; ++kgi) s += part[kgi * 16 + t];
        sc[t] = s;
    }
    __syncthreads();
    if (t == 0) {
        int i0 = 0; float v0 = sc[0];
        #pragma unroll
        for (int i = 1; i < E_; ++i) { if (sc[i] > v0) { v0 = sc[i]; i0 = i; } }
        int i1 = -1; float v1 = -INFINITY;
        #pragma unroll
        for (int i = 0; i < E_; ++i) {
            if (i == i0) continue;
            if (sc[i] > v1) { v1 = sc[i]; i1 = i; }
        }
        float e1 = expf((v1 - v0) * 0.5f);
        float inv = 1.0f / (1.0f + e1);
        out[b * 2 + 0] = (float)i0;
        out[b * 2 + 1] = (float)i1;
        out[2 * B_ + b * 2 + 0] = inv;
        out[2 * B_ + b * 2 + 1] = e1 * inv;
    }
}

extern "C" void kernel_launch(void* const* d_in, const int* in_sizes, int n_in,
                              void* d_out, int out_size, void* d_ws, size_t ws_size,
                              hipStream_t stream) {
    const float* x     = (const float*)d_in[0];
    const float* w1    = (const float*)d_in[1];
    const float* b1    = (const float*)d_in[2];
    const float* bn1_g = (const float*)d_in[3];
    const float* bn1_b = (const float*)d_in[4];
    const float* bn1_m = (const float*)d_in[5];
    const float* bn1_v = (const float*)d_in[6];
    const float* caw1  = (const float*)d_in[7];
    const float* cab1  = (const float*)d_in[8];
    const float* caw2  = (const float*)d_in[9];
    const float* cab2  = (const float*)d_in[10];
    const float* w2    = (const float*)d_in[11];
    const float* b2    = (const float*)d_in[12];
    const float* bn2_g = (const float*)d_in[13];
    const float* bn2_b = (const float*)d_in[14];
    const float* bn2_m = (const float*)d_in[15];
    const float* bn2_v = (const float*)d_in[16];
    const float* w3    = (const float*)d_in[17];
    const float* b3    = (const float*)d_in[18];

    float* ws  = (float*)d_ws;
    float* gT  = ws;                          // [768][64]
    float* h1T = ws + 49152;                  // [1536][64]
    float* rT  = ws + 49152 + 98304;          // [96][64]
    float* h2T = ws + 49152 + 98304 + 6144;   // [768][64]
    float* out = (float*)d_out;

    pool_kernel<<<(B_ * C_) / 4, 256, 0, stream>>>(x, gT);
    gemv2_kernel<C_, true><<<C2_ / 2, 512, 0, stream>>>(
        gT, w1, b1, bn1_g, bn1_b, bn1_m, bn1_v, h1T);
    gemv2_kernel<C2_, false><<<R_ / 2, 512, 0, stream>>>(
        h1T, caw1, cab1, nullptr, nullptr, nullptr, nullptr, rT);
    gate_kernel<<<C2_ / 8, 512, 0, stream>>>(rT, caw2, cab2, h1T);
    gemv2_kernel<C2_, true><<<C_ / 2, 512, 0, stream>>>(
        h1T, w2, b2, bn2_g, bn2_b, bn2_m, bn2_v, h2T);
    l5_kernel<<<B_, 256, 0, stream>>>(h2T, w3, b3, out);
}